// Round 3
// baseline (2840.901 us; speedup 1.0000x reference)
//
#include <hip/hip_runtime.h>

#define UU 512
#define EE 300
#define VTT 30000
#define SS 64
#define TT 32
#define BB 32

typedef unsigned short u16;
typedef short s8v __attribute__((ext_vector_type(8)));
typedef unsigned short us4 __attribute__((ext_vector_type(4)));
typedef float f4v __attribute__((ext_vector_type(4)));

__device__ __forceinline__ float bf2f(u16 v){
  union { unsigned u; float f; } x; x.u = ((unsigned)v) << 16; return x.f;
}
__device__ __forceinline__ u16 f2bf(float f){
  union { float f; unsigned u; } x; x.f = f;
  unsigned r = x.u + 0x7FFFu + ((x.u >> 16) & 1u);
  return (u16)(r >> 16);
}
__device__ __forceinline__ float sigm(float x){ return 1.f / (1.f + __expf(-x)); }
__device__ __forceinline__ float ftanh(float x){
  float t = __expf(-2.f * fabsf(x));
  float r = (1.f - t) / (1.f + t);
  return x < 0.f ? -r : r;
}
__device__ __forceinline__ int imin(int a, int b){ return a < b ? a : b; }

// async global->LDS, 16B per lane; LDS dest = wave-uniform base + lane*16B
__device__ __forceinline__ void gll16(const u16* g, u16* l){
  __builtin_amdgcn_global_load_lds(
      (const __attribute__((address_space(1))) void*)g,
      (__attribute__((address_space(3))) void*)l, 16, 0, 0);
}

// device-scope grid barrier (sense via monotone generation counter).
// All participating blocks must be co-resident (grids sized << 256 CUs).
__device__ __forceinline__ void gbar(unsigned* cnt, unsigned* gen,
                                     unsigned nblk, unsigned target){
  __syncthreads();
  if(threadIdx.x == 0){
    __threadfence();                               // release prior stores
    if(atomicAdd(cnt, 1u) == nblk - 1u){
      __hip_atomic_store(cnt, 0u, __ATOMIC_RELAXED, __HIP_MEMORY_SCOPE_AGENT);
      __threadfence();
      __hip_atomic_store(gen, target, __ATOMIC_RELEASE, __HIP_MEMORY_SCOPE_AGENT);
    } else {
      while(__hip_atomic_load(gen, __ATOMIC_ACQUIRE, __HIP_MEMORY_SCOPE_AGENT) < target)
        __builtin_amdgcn_s_sleep(2);
    }
    __threadfence();                               // acquire for following loads
  }
  __syncthreads();
}

// ---------------- init: zero hF, out row0, Xl pad cols, hbf, barriers ------------
__global__ void k_init(float* __restrict__ hF, float* __restrict__ out,
                       u16* __restrict__ Xl, float* __restrict__ hbfF,
                       unsigned* __restrict__ bars){
  int i = blockIdx.x * 256 + threadIdx.x;
  if(i < 4*BB*UU) hF[i] = 0.f;
  if(i < BB*VTT) out[i] = 0.f;
  if(i < 992*20){
    int r = i / 20, c = i - r*20;
    Xl[(size_t)r*1856 + 1836 + c] = 0;
  }
  if(i < 65536) hbfF[i] = 0.f;
  if(i < 128) bars[i] = 0u;
}

// ---------------- Xsrc[tb][k] = bf16(emb_src[source[tb]][k]), K padded to 320 ----
__global__ void k_embsrc(const float* __restrict__ emb, const int* __restrict__ src,
                         u16* __restrict__ X){
  int i = blockIdx.x * 256 + threadIdx.x;
  if(i >= SS*BB*320) return;
  int tb = i / 320, k = i - tb*320;
  X[i] = (k < EE) ? f2bf(emb[(size_t)src[tb]*EE + k]) : (u16)0;
}

// ---------------- EmbT + Xl emb cols ----------------
__global__ void k_embT(const float* __restrict__ emb, const int* __restrict__ tgt,
                       u16* __restrict__ X, u16* __restrict__ Xl){
  int i = blockIdx.x * 256 + threadIdx.x;
  if(i >= 992*320) return;
  int r = i / 320, k = i - r*320;
  u16 v = (k < EE) ? f2bf(emb[(size_t)tgt[r]*EE + k]) : (u16)0;
  X[i] = v;
  if(k < EE) Xl[(size_t)r*1856 + 1536 + k] = v;
}

// ---------------- fp32 -> bf16 convert with zero col-pad (take%4==0) -------------
__global__ void k_cvt(const float* __restrict__ src, int srs, int cofs, int take,
                      u16* __restrict__ dst, int cdst){
  int r = blockIdx.x;
  const float* s = src + (size_t)r*srs + cofs;
  u16* d = dst + (size_t)r*cdst;
  for(int c4 = threadIdx.x; c4 < (cdst >> 2); c4 += blockDim.x){
    us4 o;
    if(c4*4 < take){
      f4v v = *(const f4v*)(s + c4*4);
      o[0]=f2bf(v[0]); o[1]=f2bf(v[1]); o[2]=f2bf(v[2]); o[3]=f2bf(v[3]);
    } else o = (us4){0,0,0,0};
    *(us4*)(d + c4*4) = o;
  }
}

// ---------------- weight prep: fragment-linear hi/lo bf16 pack -------------------
__global__ void k_wprep(const float* __restrict__ W, int ldw, int colofs,
                        int gstr, int ng, int ubstr, int NKF, int passes,
                        int total, u16* __restrict__ out){
  int flat = blockIdx.x * 256 + threadIdx.x;
  if(flat >= total) return;
  int l = flat & 63;
  int g = (flat >> 6) % ng;
  int kf = (flat / (64*ng)) % NKF;
  int ub = flat / (64*ng*NKF);
  int row = g*gstr + ub*ubstr + (l & 15);
  int col = colofs + kf*32 + ((l >> 4) << 3);
  const float* s = W + (size_t)row*ldw + col;
  f4v v0 = *(const f4v*)(s);
  f4v v1 = *(const f4v*)(s + 4);
  size_t base = ((((size_t)(ub*NKF + kf)*ng + g)*passes)*64 + l)*8;
  us4 h0, h1;
  h0[0]=f2bf(v0[0]); h0[1]=f2bf(v0[1]); h0[2]=f2bf(v0[2]); h0[3]=f2bf(v0[3]);
  h1[0]=f2bf(v1[0]); h1[1]=f2bf(v1[1]); h1[2]=f2bf(v1[2]); h1[3]=f2bf(v1[3]);
  *(us4*)(out + base) = h0;
  *(us4*)(out + base + 4) = h1;
  if(passes == 2){
    us4 l0, l1;
    l0[0]=f2bf(v0[0]-bf2f(h0[0])); l0[1]=f2bf(v0[1]-bf2f(h0[1]));
    l0[2]=f2bf(v0[2]-bf2f(h0[2])); l0[3]=f2bf(v0[3]-bf2f(h0[3]));
    l1[0]=f2bf(v1[0]-bf2f(h1[0])); l1[1]=f2bf(v1[1]-bf2f(h1[1]));
    l1[2]=f2bf(v1[2]-bf2f(h1[2])); l1[3]=f2bf(v1[3]-bf2f(h1[3]));
    *(us4*)(out + base + 512) = l0;
    *(us4*)(out + base + 516) = l1;
  }
}

// ---------------- bf16xbf16 GEMM-BT body (m97 structure) -------------------------
__device__ __forceinline__ void gemm_body(int m0, int n0,
    const u16* __restrict__ A, int lda,
    const u16* __restrict__ B, int ldb,
    const float* __restrict__ bias,
    float* __restrict__ C, int ldc, int mofs,
    int M, int N, int K){
  int tid = threadIdx.x;
  int lane = tid & 63, wave = tid >> 6;
  int wm = wave >> 1, wn = wave & 1;
  int lm = lane & 15, lq = lane >> 4;
  __shared__ __align__(16) u16 Asl[128*32];
  __shared__ __align__(16) u16 Bsl[128*32];
  f4v acc[4][4];
  #pragma unroll
  for(int i = 0; i < 4; i++)
    #pragma unroll
    for(int j = 0; j < 4; j++) acc[i][j] = (f4v){0.f,0.f,0.f,0.f};
  int e0 = (wave*2+0)*512 + lane*8;
  int e1 = (wave*2+1)*512 + lane*8;
  int r0 = e0 >> 5, c0 = e0 & 31;
  int r1 = e1 >> 5, c1 = e1 & 31;
  const u16* Ag0 = A + (size_t)imin(m0+r0, M-1)*lda + c0;
  const u16* Ag1 = A + (size_t)imin(m0+r1, M-1)*lda + c1;
  const u16* Bg0 = B + (size_t)imin(n0+r0, N-1)*ldb + c0;
  const u16* Bg1 = B + (size_t)imin(n0+r1, N-1)*ldb + c1;
  u16* Al0 = Asl + (wave*2+0)*512;
  u16* Al1 = Asl + (wave*2+1)*512;
  u16* Bl0 = Bsl + (wave*2+0)*512;
  u16* Bl1 = Bsl + (wave*2+1)*512;
  for(int k0 = 0; k0 < K; k0 += 32){
    __syncthreads();
    gll16(Ag0 + k0, Al0); gll16(Ag1 + k0, Al1);
    gll16(Bg0 + k0, Bl0); gll16(Bg1 + k0, Bl1);
    __syncthreads();
    s8v af[4], bfv[4];
    #pragma unroll
    for(int mi = 0; mi < 4; mi++)
      af[mi] = *(const s8v*)(Asl + (wm*64 + mi*16 + lm)*32 + lq*8);
    #pragma unroll
    for(int nj = 0; nj < 4; nj++)
      bfv[nj] = *(const s8v*)(Bsl + (wn*64 + nj*16 + lm)*32 + lq*8);
    #pragma unroll
    for(int mi = 0; mi < 4; mi++)
      #pragma unroll
      for(int nj = 0; nj < 4; nj++)
        acc[mi][nj] = __builtin_amdgcn_mfma_f32_16x16x32_bf16(af[mi], bfv[nj], acc[mi][nj], 0, 0, 0);
  }
  #pragma unroll
  for(int nj = 0; nj < 4; nj++){
    int n = n0 + wn*64 + nj*16 + lm;
    if(n < N){
      float bv = bias[n];
      #pragma unroll
      for(int mi = 0; mi < 4; mi++){
        #pragma unroll
        for(int rg = 0; rg < 4; rg++){
          int m = m0 + wm*64 + mi*16 + lq*4 + rg;
          if(m < M) C[(size_t)(m + mofs)*ldc + n] = acc[mi][nj][rg] + bv;
        }
      }
    }
  }
}

__global__ __launch_bounds__(256) void k_gemm_bf(
    const u16* __restrict__ A, int lda, const u16* __restrict__ B, int ldb,
    const float* __restrict__ bias, float* __restrict__ C, int ldc, int mofs,
    int M, int N, int K){
  gemm_body(blockIdx.x*128, blockIdx.y*128, A, lda, B, ldb, bias, C, ldc, mofs, M, N, K);
}

// logits GEMM: 1D grid, XCD-bijective swizzle
__global__ __launch_bounds__(256) void k_gemm_lg(
    const u16* __restrict__ A, int lda, const u16* __restrict__ B, int ldb,
    const float* __restrict__ bias, float* __restrict__ C, int ldc, int mofs,
    int M, int N, int K){
  int id = blockIdx.x;
  int x = id & 7, j = id >> 3;
  int m = j & 7, p = (j & ~7) | x;
  if(p * 128 >= N) return;
  gemm_body(m*128, p*128, A, lda, B, ldb, bias, C, ldc, mofs, M, N, K);
}

// ---------------- PERSISTENT encoder: 64 blocks x 1 wave, weights LDS-resident ---
// block=(dir,ub); per step: stage A(32KB), 288 MFMA, epilogue, per-dir grid barrier
__global__ __launch_bounds__(64) void k_encp(
    const float* __restrict__ gi_f, const float* __restrict__ gi_b,
    const u16* __restrict__ Wenc,
    const float* __restrict__ bhh_f, const float* __restrict__ bhh_b,
    float* __restrict__ hF, u16* __restrict__ hbf, u16* __restrict__ enc,
    unsigned* __restrict__ bars){
  int dir = blockIdx.x >> 5;
  int ub  = blockIdx.x & 31;
  int l = threadIdx.x;
  const float* giB = dir ? gi_b : gi_f;
  const float* bhh = dir ? bhh_b : bhh_f;
  const u16* Wslab = Wenc + ((size_t)(dir*32 + ub))*49152;
  unsigned* cnt = bars + dir*32;
  unsigned* gen = bars + dir*32 + 16;
  __shared__ __align__(16) u16 WL[49152];   // 96 KB: both K-chunks of this slab
  __shared__ __align__(16) u16 Ab[16384];   // 32 KB: one A chunk (hi+lo)
  // one-time weight stage
  #pragma unroll 1
  for(int i = 0; i < 96; i++) gll16(Wslab + i*512 + l*8, WL + i*512);
  int lm = l & 15, lq = l >> 4;
  for(int t = 0; t < SS; t++){
    int par = t & 1;
    int te = dir ? (SS-1-t) : t;
    const float* gi = giB + (size_t)(te*BB)*1536;
    const u16* Asrc = hbf + (size_t)(par*2 + dir)*32768;
    u16* Adst       = hbf + (size_t)((par^1)*2 + dir)*32768;
    const float* hin = hF + (size_t)(dir*2 + par)*(BB*UU);
    float* hout      = hF + (size_t)(dir*2 + (par^1))*(BB*UU);
    f4v acc[2][3];
    #pragma unroll
    for(int i = 0; i < 2; i++)
      #pragma unroll
      for(int j = 0; j < 3; j++) acc[i][j] = (f4v){0.f,0.f,0.f,0.f};
    for(int c = 0; c < 2; c++){
      __syncthreads();
      #pragma unroll 1
      for(int i = 0; i < 32; i++) gll16(Asrc + c*16384 + i*512 + l*8, Ab + i*512);
      __syncthreads();
      #pragma unroll
      for(int kf = 0; kf < 8; kf++){
        s8v a[2][2], bw[3][2];
        #pragma unroll
        for(int mf = 0; mf < 2; mf++)
          #pragma unroll
          for(int p = 0; p < 2; p++)
            a[mf][p] = *(const s8v*)(Ab + ((kf*2+mf)*2+p)*512 + l*8);
        #pragma unroll
        for(int g = 0; g < 3; g++)
          #pragma unroll
          for(int p = 0; p < 2; p++)
            bw[g][p] = *(const s8v*)(WL + c*24576 + ((kf*3+g)*2+p)*512 + l*8);
        #pragma unroll
        for(int mf = 0; mf < 2; mf++)
          #pragma unroll
          for(int g = 0; g < 3; g++){
            acc[mf][g] = __builtin_amdgcn_mfma_f32_16x16x32_bf16(a[mf][0], bw[g][0], acc[mf][g], 0, 0, 0);
            acc[mf][g] = __builtin_amdgcn_mfma_f32_16x16x32_bf16(a[mf][1], bw[g][0], acc[mf][g], 0, 0, 0);
            acc[mf][g] = __builtin_amdgcn_mfma_f32_16x16x32_bf16(a[mf][0], bw[g][1], acc[mf][g], 0, 0, 0);
          }
      }
    }
    __syncthreads();
    float* ghs = (float*)Ab;              // 6 KB, A chunk dead
    #pragma unroll
    for(int mf = 0; mf < 2; mf++)
      #pragma unroll
      for(int g = 0; g < 3; g++)
        #pragma unroll
        for(int rg = 0; rg < 4; rg++)
          ghs[(g*16 + lm)*32 + mf*16 + lq*4 + rg] = acc[mf][g][rg];
    __syncthreads();
    #pragma unroll
    for(int it = 0; it < 8; it++){
      int idx = it*64 + l;
      int b = idx & 31, ulu = idx >> 5;
      int u = ub*16 + ulu;
      float ghr = ghs[(ulu)*32 + b]      + bhh[u];
      float ghz = ghs[(16 + ulu)*32 + b] + bhh[512 + u];
      float ghn = ghs[(32 + ulu)*32 + b] + bhh[1024 + u];
      const float* gb = gi + b*1536 + u;
      float r = sigm(gb[0] + ghr);
      float z = sigm(gb[512] + ghz);
      float n = ftanh(gb[1024] + r*ghn);
      float hold = hin[b*512 + u];
      float h2 = (1.f - z)*n + z*hold;
      hout[b*512 + u] = h2;
      enc[(size_t)(b*SS + te)*1024 + dir*512 + u] = f2bf(h2);
      u16 hi = f2bf(h2);
      float lo = h2 - bf2f(hi);
      int kf = u >> 5, mf = b >> 4, l2 = ((u >> 3) & 3)*16 + (b & 15), e = u & 7;
      int base = ((kf*2 + mf)*2)*512 + l2*8 + e;
      Adst[base]       = hi;
      Adst[base + 512] = f2bf(lo);
    }
    if(t < SS-1) gbar(cnt, gen, 32u, (unsigned)(t+1));
  }
}

// ---------------- state = tanh([hf,hb] @ Wfc^T + bfc); also packs Ast[par0] ------
__global__ __launch_bounds__(256) void k_encfc(
    const float* __restrict__ h, const float* __restrict__ Wfc,
    const float* __restrict__ bfc, float* __restrict__ st, u16* __restrict__ Ast0){
  int b = blockIdx.x;
  __shared__ __align__(16) float hc[1024];
  for(int i = threadIdx.x; i < 512; i += 256){
    hc[i]       = h[0*BB*UU + b*UU + i];
    hc[512 + i] = h[2*BB*UU + b*UU + i];
  }
  __syncthreads();
  for(int u = threadIdx.x; u < 512; u += 256){
    const float* w = Wfc + u*1024;
    float a = 0.f;
    for(int k = 0; k < 1024; k += 4){
      f4v x = *(const f4v*)(hc + k);
      f4v wv = *(const f4v*)(w + k);
      a += x[0]*wv[0] + x[1]*wv[1] + x[2]*wv[2] + x[3]*wv[3];
    }
    float sv = ftanh(a + bfc[u]);
    st[b*UU + u] = sv;
    u16 hi = f2bf(sv);
    float lo = sv - bf2f(hi);
    int kf = u >> 5, mf = b >> 4, l2 = ((u >> 3) & 3)*16 + (b & 15), e = u & 7;
    int base = ((kf*2 + mf)*2)*512 + l2*8 + e;
    Ast0[base]       = hi;
    Ast0[base + 512] = f2bf(lo);
  }
}

// ---------------- PERSISTENT decoder: 32 blocks x 256 thr, 3 barriers/step -------
__global__ __launch_bounds__(256) void k_decp(
    float* __restrict__ st, const float* __restrict__ P,
    const u16* __restrict__ enc, const u16* __restrict__ Wqp,
    const u16* __restrict__ Wdc, const u16* __restrict__ Wds,
    u16* __restrict__ Actx, u16* __restrict__ Ast,
    float* __restrict__ qGp,
    const float* __restrict__ giE, const float* __restrict__ bhh,
    u16* __restrict__ Xl, unsigned* __restrict__ bars){
  int bid = blockIdx.x;
  int tid = threadIdx.x;
  int l = tid & 63, w = tid >> 6;
  int lm = l & 15, lq = l >> 4;
  unsigned* cnt = bars + 64;
  unsigned* gen = bars + 96;
  __shared__ __align__(16) u16 Ab[16384];    // 32 KB
  __shared__ __align__(16) u16 Bb[24576];    // 48 KB
  __shared__ float qvt[512];
  __shared__ float wv[64];
  unsigned tgt = 0;
  int ubq = bid >> 1, cq = bid & 1;
  const u16* Wq  = Wqp + (size_t)ubq*32768 + cq*16384;
  const u16* Wdcs = Wdc + (size_t)bid*49152;
  const u16* Wdss = Wds + (size_t)bid*49152;
  for(int t = 0; t < TT-1; t++){
    int par = t & 1;
    const u16* AstI = Ast + par*32768;
    u16* AstO       = Ast + (par^1)*32768;
    const float* stin = st + par*16384;
    float* stout      = st + (par^1)*16384;
    // ======== q phase: block=(ubq,cq), wave 0 computes one K-chunk partial ======
    if(w == 0){
      #pragma unroll 1
      for(int i = 0; i < 32; i++) gll16(AstI + cq*16384 + i*512 + l*8, Ab + i*512);
      #pragma unroll 1
      for(int i = 0; i < 32; i++) gll16(Wq + i*512 + l*8, Bb + i*512);
    }
    __syncthreads();
    if(w == 0){
      f4v qa[2][2];
      #pragma unroll
      for(int i = 0; i < 2; i++)
        #pragma unroll
        for(int j = 0; j < 2; j++) qa[i][j] = (f4v){0.f,0.f,0.f,0.f};
      #pragma unroll
      for(int kf = 0; kf < 8; kf++){
        s8v a[2][2], bw[2][2];
        #pragma unroll
        for(int mf = 0; mf < 2; mf++)
          #pragma unroll
          for(int p = 0; p < 2; p++){
            a[mf][p]  = *(const s8v*)(Ab + ((kf*2+mf)*2+p)*512 + l*8);
            bw[mf][p] = *(const s8v*)(Bb + ((kf*2+mf)*2+p)*512 + l*8);
          }
        #pragma unroll
        for(int mf = 0; mf < 2; mf++)
          #pragma unroll
          for(int g = 0; g < 2; g++){
            qa[mf][g] = __builtin_amdgcn_mfma_f32_16x16x32_bf16(a[mf][0], bw[g][0], qa[mf][g], 0, 0, 0);
            qa[mf][g] = __builtin_amdgcn_mfma_f32_16x16x32_bf16(a[mf][1], bw[g][0], qa[mf][g], 0, 0, 0);
            qa[mf][g] = __builtin_amdgcn_mfma_f32_16x16x32_bf16(a[mf][0], bw[g][1], qa[mf][g], 0, 0, 0);
          }
      }
      float* qout = qGp + cq*16384;
      #pragma unroll
      for(int mf = 0; mf < 2; mf++)
        #pragma unroll
        for(int g = 0; g < 2; g++)
          #pragma unroll
          for(int rg = 0; rg < 4; rg++){
            int a_ = ubq*32 + g*16 + lm;
            int b_ = mf*16 + lq*4 + rg;
            qout[b_*512 + (a_ & 31)*16 + (a_ >> 5)] = qa[mf][g][rg];
          }
    }
    gbar(cnt, gen, 32u, ++tgt);
    // ======== attn phase: b = bid ==============================================
    {
      int b = bid;
      for(int i = tid; i < 512; i += 256)
        qvt[i] = qGp[b*512 + i] + qGp[16384 + b*512 + i];
      __syncthreads();
      {
        int s = tid >> 2, part = tid & 3;
        const float* Pb = P + (size_t)(b*SS + s)*512 + part*128;
        float ps = 0.f;
        #pragma unroll 8
        for(int i = 0; i < 128; i += 4){
          f4v pv = *(const f4v*)(Pb + i);
          int a0 = part*128 + i;
          ps += ftanh(pv[0] + qvt[((a0+0)&31)*16 + ((a0+0)>>5)]);
          ps += ftanh(pv[1] + qvt[((a0+1)&31)*16 + ((a0+1)>>5)]);
          ps += ftanh(pv[2] + qvt[((a0+2)&31)*16 + ((a0+2)>>5)]);
          ps += ftanh(pv[3] + qvt[((a0+3)&31)*16 + ((a0+3)>>5)]);
        }
        ps += __shfl_xor(ps, 1);
        ps += __shfl_xor(ps, 2);
        if(part == 0) wv[s] = ps;
      }
      __syncthreads();
      if(tid < 64){
        float sc = wv[tid];
        float m = sc;
        for(int o = 32; o > 0; o >>= 1) m = fmaxf(m, __shfl_xor(m, o));
        float e = __expf(sc - m);
        float ssum = e;
        for(int o = 32; o > 0; o >>= 1) ssum += __shfl_xor(ssum, o);
        wv[tid] = e / ssum;
      }
      __syncthreads();
      int rowX = t*BB + b;
      #pragma unroll
      for(int jj = 0; jj < 4; jj++){
        int j = jj*256 + tid;
        float acc2 = 0.f;
        const u16* eb = enc + (size_t)(b*SS)*1024 + j;
        #pragma unroll 8
        for(int s2 = 0; s2 < SS; s2++)
          acc2 += wv[s2] * bf2f(eb[(size_t)s2*1024]);
        u16 cb = f2bf(acc2);
        Xl[(size_t)rowX*1856 + 512 + j] = cb;
        int kf = j >> 5, mf = b >> 4, l2 = ((j >> 3) & 3)*16 + (b & 15), e = j & 7;
        Actx[(size_t)(kf*2 + mf)*512 + l2*8 + e] = cb;
      }
    }
    gbar(cnt, gen, 32u, ++tgt);
    // ======== gru phase: ub = bid; kf split across 4 waves =====================
    {
      int ub = bid;
      f4v accI[2][3], accH[2][3];
      #pragma unroll
      for(int i = 0; i < 2; i++)
        #pragma unroll
        for(int j = 0; j < 3; j++){
          accI[i][j] = (f4v){0.f,0.f,0.f,0.f};
          accH[i][j] = (f4v){0.f,0.f,0.f,0.f};
        }
      #pragma unroll 1
      for(int sp = 0; sp < 4; sp++){
        const u16* Asub = (sp < 2) ? (Actx + sp*16384) : (AstI + (sp-2)*16384);
        const u16* Bsub = (sp < 2) ? (Wdcs + sp*24576) : (Wdss + (sp-2)*24576);
        __syncthreads();
        #pragma unroll 1
        for(int i = 0; i < 20; i++){
          int r = w*20 + i;
          const u16* src = (r < 32) ? (Asub + r*512) : (Bsub + (size_t)(r-32)*512);
          u16* dst = (r < 32) ? (Ab + r*512) : (Bb + (r-32)*512);
          gll16(src + l*8, dst);
        }
        __syncthreads();
        if(sp < 2){
          #pragma unroll
          for(int kk = 0; kk < 4; kk++){
            int kf = w*4 + kk;
            s8v a0 = *(const s8v*)(Ab + (kf*2+0)*512 + l*8);
            s8v a1 = *(const s8v*)(Ab + (kf*2+1)*512 + l*8);
            s8v b0 = *(const s8v*)(Bb + (kf*3+0)*512 + l*8);
            s8v b1 = *(const s8v*)(Bb + (kf*3+1)*512 + l*8);
            s8v b2 = *(const s8v*)(Bb + (kf*3+2)*512 + l*8);
            accI[0][0] = __builtin_amdgcn_mfma_f32_16x16x32_bf16(a0, b0, accI[0][0], 0, 0, 0);
            accI[0][1] = __builtin_amdgcn_mfma_f32_16x16x32_bf16(a0, b1, accI[0][1], 0, 0, 0);
            accI[0][2] = __builtin_amdgcn_mfma_f32_16x16x32_bf16(a0, b2, accI[0][2], 0, 0, 0);
            accI[1][0] = __builtin_amdgcn_mfma_f32_16x16x32_bf16(a1, b0, accI[1][0], 0, 0, 0);
            accI[1][1] = __builtin_amdgcn_mfma_f32_16x16x32_bf16(a1, b1, accI[1][1], 0, 0, 0);
            accI[1][2] = __builtin_amdgcn_mfma_f32_16x16x32_bf16(a1, b2, accI[1][2], 0, 0, 0);
          }
        } else {
          #pragma unroll
          for(int kk = 0; kk < 2; kk++){
            int kf = w*2 + kk;
            s8v a[2][2], bw[3][2];
            #pragma unroll
            for(int mf = 0; mf < 2; mf++)
              #pragma unroll
              for(int p = 0; p < 2; p++)
                a[mf][p] = *(const s8v*)(Ab + ((kf*2+mf)*2+p)*512 + l*8);
            #pragma unroll
            for(int g = 0; g < 3; g++)
              #pragma unroll
              for(int p = 0; p < 2; p++)
                bw[g][p] = *(const s8v*)(Bb + ((kf*3+g)*2+p)*512 + l*8);
            #pragma unroll
            for(int mf = 0; mf < 2; mf++)
              #pragma unroll
              for(int g = 0; g < 3; g++){
                accH[mf][g] = __builtin_amdgcn_mfma_f32_16x16x32_bf16(a[mf][0], bw[g][0], accH[mf][g], 0, 0, 0);
                accH[mf][g] = __builtin_amdgcn_mfma_f32_16x16x32_bf16(a[mf][1], bw[g][0], accH[mf][g], 0, 0, 0);
                accH[mf][g] = __builtin_amdgcn_mfma_f32_16x16x32_bf16(a[mf][0], bw[g][1], accH[mf][g], 0, 0, 0);
              }
          }
        }
      }
      __syncthreads();
      float* ghsI = (float*)Bb;                 // 4 x 6 KB partials
      float* ghsH = (float*)Ab;                 // 4 x 6 KB partials
      #pragma unroll
      for(int mf = 0; mf < 2; mf++)
        #pragma unroll
        for(int g = 0; g < 3; g++)
          #pragma unroll
          for(int rg = 0; rg < 4; rg++){
            int o = w*1536 + (g*16 + lm)*32 + mf*16 + lq*4 + rg;
            ghsI[o] = accI[mf][g][rg];
            ghsH[o] = accH[mf][g][rg];
          }
      __syncthreads();
      #pragma unroll
      for(int it = 0; it < 2; it++){
        int idx = it*256 + tid;
        int b2 = idx & 31, ulu = idx >> 5;
        int u = ub*16 + ulu;
        int xrow = t*BB + b2;
        float gIr=0.f, gIz=0.f, gIn=0.f, gHr=0.f, gHz=0.f, gHn=0.f;
        #pragma unroll
        for(int ww = 0; ww < 4; ww++){
          int o = ww*1536;
          gIr += ghsI[o + (ulu)*32 + b2];
          gIz += ghsI[o + (16 + ulu)*32 + b2];
          gIn += ghsI[o + (32 + ulu)*32 + b2];
          gHr += ghsH[o + (ulu)*32 + b2];
          gHz += ghsH[o + (16 + ulu)*32 + b2];
          gHn += ghsH[o + (32 + ulu)*32 + b2];
        }
        const float* ge = giE + (size_t)xrow*1536 + u;
        gIr += ge[0]; gIz += ge[512]; gIn += ge[1024];
        gHr += bhh[u]; gHz += bhh[512 + u]; gHn += bhh[1024 + u];
        float r = sigm(gIr + gHr);
        float z = sigm(gIz + gHz);
        float n = ftanh(gIn + r*gHn);
        float hold = stin[b2*512 + u];
        float h2 = (1.f - z)*n + z*hold;
        stout[b2*512 + u] = h2;
        Xl[(size_t)xrow*1856 + u] = f2bf(h2);
        u16 hi = f2bf(h2);
        float lo = h2 - bf2f(hi);
        int kf2 = u >> 5, mf2 = b2 >> 4, l2 = ((u >> 3) & 3)*16 + (b2 & 15), e = u & 7;
        int base = ((kf2*2 + mf2)*2)*512 + l2*8 + e;
        AstO[base]       = hi;
        AstO[base + 512] = f2bf(lo);
      }
    }
    if(t < TT-2) gbar(cnt, gen, 32u, ++tgt);
  }
}

extern "C" void kernel_launch(void* const* d_in, const int* in_sizes, int n_in,
                              void* d_out, int out_size, void* d_ws, size_t ws_size,
                              hipStream_t stream){
  (void)in_sizes; (void)n_in; (void)out_size; (void)ws_size;
  const float* emb_src = (const float*)d_in[0];
  const float* emb_trg = (const float*)d_in[1];
  const float* eWih_f  = (const float*)d_in[2];
  const float* eWhh_f  = (const float*)d_in[3];
  const float* ebih_f  = (const float*)d_in[4];
  const float* ebhh_f  = (const float*)d_in[5];
  const float* eWih_b  = (const float*)d_in[6];
  const float* eWhh_b  = (const float*)d_in[7];
  const float* ebih_b  = (const float*)d_in[8];
  const float* ebhh_b  = (const float*)d_in[9];
  const float* Wfc     = (const float*)d_in[10];
  const float* bfc     = (const float*)d_in[11];
  const float* attn_W  = (const float*)d_in[12];
  const float* attn_b  = (const float*)d_in[13];
  const float* dWih    = (const float*)d_in[14];
  const float* dWhh    = (const float*)d_in[15];
  const float* dbih    = (const float*)d_in[16];
  const float* dbhh    = (const float*)d_in[17];
  const float* dWfc    = (const float*)d_in[18];
  const float* dbfc    = (const float*)d_in[19];
  const int* source    = (const int*)d_in[20];
  const int* target    = (const int*)d_in[21];
  float* out = (float*)d_out;
  float* wsf = (float*)d_ws;

  // ---- f32 prefix ----
  float* P    = wsf;                                   // 2048x512
  float* hF   = P + (size_t)2048*512;                  // 2dir x 2par x 32 x 512
  float* st   = hF + 65536;                            // 2par x 32 x 512
  float* qGp  = st + 32768;                            // 2 x 32x512 partials
  float* giE  = qGp + 32768;                           // 992x1536
  // ---- u16 region (starts 16B-aligned) ----
  u16* enc   = (u16*)(giE + (size_t)992*1536);         // (B,S,2U)
  u16* Xl    = enc + (size_t)2048*1024;                // 992x1856
  u16* Xsrc  = Xl + (size_t)992*1856;                  // 2048x320
  u16* WihF  = Xsrc + (size_t)2048*320;                // 1536x320
  u16* WihB  = WihF + (size_t)1536*320;
  u16* WihE  = WihB + (size_t)1536*320;
  u16* AttnW = WihE + (size_t)1536*320;                // 512x1024
  u16* Wenc  = AttnW + (size_t)512*1024;               // 2dir x 32ub x 49152
  u16* Wdc   = Wenc + (size_t)2*32*49152;              // 32ub x 49152
  u16* Wds   = Wdc + (size_t)32*49152;                 // 32ub x 49152
  u16* Wqp   = Wds + (size_t)32*49152;                 // 16ub x 32768
  u16* hbf   = Wqp + (size_t)16*32768;                 // 2par x 2dir x 32768
  u16* Actx  = hbf + (size_t)4*32768;                  // 32768
  u16* Ast   = Actx + 32768;                           // 2par x 32768
  unsigned* bars = (unsigned*)(Ast + (size_t)2*32768); // 128 u32
  u16* endu  = (u16*)(bars + 128);
  // ---- tail: gi (encoder-only) overlapped later by WfcB ----
  float* gi_f = (float*)endu;                          // 2048x1536
  float* gi_b = gi_f + (size_t)2048*1536;
  u16* WfcB  = endu;                                   // 30000x1856 (overlaps gi)
  u16* EmbT  = Xsrc;                                   // reuse after gi GEMMs

  k_init<<<3750, 256, 0, stream>>>(hF, out, Xl, (float*)hbf, bars);
  k_embsrc<<<2560, 256, 0, stream>>>(emb_src, source, Xsrc);
  k_cvt<<<1536, 256, 0, stream>>>(eWih_f, 300, 0, 300, WihF, 320);
  k_cvt<<<1536, 256, 0, stream>>>(eWih_b, 300, 0, 300, WihB, 320);
  k_cvt<<<1536, 256, 0, stream>>>(dWih, 1324, 0, 300, WihE, 320);
  k_cvt<<<512, 256, 0, stream>>>(attn_W, 1536, 512, 1024, AttnW, 1024);
  // fragment-linear recurrent weights
  k_wprep<<<384, 256, 0, stream>>>(eWhh_f, 512, 0, 512, 3, 16, 16, 2, 98304, Wenc);
  k_wprep<<<384, 256, 0, stream>>>(eWhh_b, 512, 0, 512, 3, 16, 16, 2, 98304, Wenc + (size_t)32*49152);
  k_wprep<<<768, 256, 0, stream>>>(dWih, 1324, 300, 512, 3, 16, 32, 1, 196608, Wdc);
  k_wprep<<<384, 256, 0, stream>>>(dWhh, 512, 0, 512, 3, 16, 16, 2, 98304, Wds);
  k_wprep<<<128, 256, 0, stream>>>(attn_W, 1536, 0, 16, 2, 32, 16, 2, 32768, Wqp);
  // gi = Xsrc @ Wih^T + bih (both dirs)
  k_gemm_bf<<<dim3(16,12), 256, 0, stream>>>(Xsrc, 320, WihF, 320, ebih_f, gi_f, 1536, 0, 2048, 1536, 320);
  k_gemm_bf<<<dim3(16,12), 256, 0, stream>>>(Xsrc, 320, WihB, 320, ebih_b, gi_b, 1536, 0, 2048, 1536, 320);
  // persistent encoder: all 64 steps in one launch
  k_encp<<<64, 64, 0, stream>>>(gi_f, gi_b, Wenc, ebhh_f, ebhh_b, hF, hbf, enc, bars);
  k_encfc<<<BB, 256, 0, stream>>>(hF, Wfc, bfc, st, Ast);
  k_gemm_bf<<<dim3(16,4), 256, 0, stream>>>(enc, 1024, AttnW, 1024, attn_b, P, 512, 0, 2048, 512, 1024);
  k_embT<<<1240, 256, 0, stream>>>(emb_trg, target, EmbT, Xl);
  k_gemm_bf<<<dim3(8,12), 256, 0, stream>>>(EmbT, 320, WihE, 320, dbih, giE, 1536, 0, 992, 1536, 320);
  // persistent decoder: all 31 steps in one launch
  k_decp<<<32, 256, 0, stream>>>(st, P, enc, Wqp, Wdc, Wds, Actx, Ast, qGp,
                                 giE, dbhh, Xl, bars);
  // WfcB cvt deferred here: overlaps (dead) gi region
  k_cvt<<<30000, 256, 0, stream>>>(dWfc, 1836, 0, 1836, WfcB, 1856);
  k_gemm_lg<<<1920, 256, 0, stream>>>(Xl, 1856, WfcB, 1856, dbfc, out, VTT, 32, 992, VTT, 1856);
}

// Round 4
// 2498.767 us; speedup vs baseline: 1.1369x; 1.1369x over previous
//
#include <hip/hip_runtime.h>

#define UU 512
#define EE 300
#define VTT 30000
#define SS 64
#define TT 32
#define BB 32

typedef unsigned short u16;
typedef short s8v __attribute__((ext_vector_type(8)));
typedef unsigned short us4 __attribute__((ext_vector_type(4)));
typedef float f4v __attribute__((ext_vector_type(4)));

__device__ __forceinline__ float bf2f(u16 v){
  union { unsigned u; float f; } x; x.u = ((unsigned)v) << 16; return x.f;
}
__device__ __forceinline__ u16 f2bf(float f){
  union { float f; unsigned u; } x; x.f = f;
  unsigned r = x.u + 0x7FFFu + ((x.u >> 16) & 1u);
  return (u16)(r >> 16);
}
__device__ __forceinline__ float sigm(float x){ return 1.f / (1.f + __expf(-x)); }
__device__ __forceinline__ float ftanh(float x){
  float t = __expf(-2.f * fabsf(x));
  float r = (1.f - t) / (1.f + t);
  return x < 0.f ? -r : r;
}
__device__ __forceinline__ int imin(int a, int b){ return a < b ? a : b; }

// async global->LDS, 16B per lane; LDS dest = wave-uniform base + lane*16B
__device__ __forceinline__ void gll16(const u16* g, u16* l){
  __builtin_amdgcn_global_load_lds(
      (const __attribute__((address_space(1))) void*)g,
      (__attribute__((address_space(3))) void*)l, 16, 0, 0);
}

// grid barrier, one counter per barrier INSTANCE (no reset, no generation race).
// Release fetch_add -> s_waitcnt + buffer_wbl2 (flush dirty to L3) WITHOUT the
// L2 invalidate a full fence would add. Readers consume only step-versioned
// addresses (never before touched by their XCD) -> plain loads see fresh data.
__device__ __forceinline__ void gbarv(unsigned* c, unsigned nblk){
  __syncthreads();                 // drains each wave's vmcnt (stores in L2)
  if(threadIdx.x == 0){
    __hip_atomic_fetch_add(c, 1u, __ATOMIC_RELEASE, __HIP_MEMORY_SCOPE_AGENT);
    while(__hip_atomic_load(c, __ATOMIC_RELAXED, __HIP_MEMORY_SCOPE_AGENT) < nblk)
      __builtin_amdgcn_s_sleep(2);
  }
  __syncthreads();
  asm volatile("" ::: "memory");
}

// ---------------- init: zero out row0, Xl pad cols, hbfv[t=0], barriers ----------
__global__ void k_init(float* __restrict__ out, u16* __restrict__ Xl,
                       float* __restrict__ hbf0, unsigned* __restrict__ bars){
  int i = blockIdx.x * 256 + threadIdx.x;
  if(i < BB*VTT) out[i] = 0.f;
  if(i < 992*20){
    int r = i / 20, c = i - r*20;
    Xl[(size_t)r*1856 + 1836 + c] = 0;
  }
  if(i < 32768) hbf0[i] = 0.f;     // hbfv slots (t=0, dir=0/1): 2x32768 u16
  if(i < 256) bars[i] = 0u;
}

// ---------------- Xsrc[tb][k] = bf16(emb_src[source[tb]][k]), K padded to 320 ----
__global__ void k_embsrc(const float* __restrict__ emb, const int* __restrict__ src,
                         u16* __restrict__ X){
  int i = blockIdx.x * 256 + threadIdx.x;
  if(i >= SS*BB*320) return;
  int tb = i / 320, k = i - tb*320;
  X[i] = (k < EE) ? f2bf(emb[(size_t)src[tb]*EE + k]) : (u16)0;
}

// ---------------- EmbT + Xl emb cols ----------------
__global__ void k_embT(const float* __restrict__ emb, const int* __restrict__ tgt,
                       u16* __restrict__ X, u16* __restrict__ Xl){
  int i = blockIdx.x * 256 + threadIdx.x;
  if(i >= 992*320) return;
  int r = i / 320, k = i - r*320;
  u16 v = (k < EE) ? f2bf(emb[(size_t)tgt[r]*EE + k]) : (u16)0;
  X[i] = v;
  if(k < EE) Xl[(size_t)r*1856 + 1536 + k] = v;
}

// ---------------- fp32 -> bf16 convert with zero col-pad (take%4==0) -------------
__global__ void k_cvt(const float* __restrict__ src, int srs, int cofs, int take,
                      u16* __restrict__ dst, int cdst){
  int r = blockIdx.x;
  const float* s = src + (size_t)r*srs + cofs;
  u16* d = dst + (size_t)r*cdst;
  for(int c4 = threadIdx.x; c4 < (cdst >> 2); c4 += blockDim.x){
    us4 o;
    if(c4*4 < take){
      f4v v = *(const f4v*)(s + c4*4);
      o[0]=f2bf(v[0]); o[1]=f2bf(v[1]); o[2]=f2bf(v[2]); o[3]=f2bf(v[3]);
    } else o = (us4){0,0,0,0};
    *(us4*)(d + c4*4) = o;
  }
}

// ---------------- weight prep: fragment-linear hi/lo bf16 pack -------------------
__global__ void k_wprep(const float* __restrict__ W, int ldw, int colofs,
                        int gstr, int ng, int ubstr, int NKF, int passes,
                        int total, u16* __restrict__ out){
  int flat = blockIdx.x * 256 + threadIdx.x;
  if(flat >= total) return;
  int l = flat & 63;
  int g = (flat >> 6) % ng;
  int kf = (flat / (64*ng)) % NKF;
  int ub = flat / (64*ng*NKF);
  int row = g*gstr + ub*ubstr + (l & 15);
  int col = colofs + kf*32 + ((l >> 4) << 3);
  const float* s = W + (size_t)row*ldw + col;
  f4v v0 = *(const f4v*)(s);
  f4v v1 = *(const f4v*)(s + 4);
  size_t base = ((((size_t)(ub*NKF + kf)*ng + g)*passes)*64 + l)*8;
  us4 h0, h1;
  h0[0]=f2bf(v0[0]); h0[1]=f2bf(v0[1]); h0[2]=f2bf(v0[2]); h0[3]=f2bf(v0[3]);
  h1[0]=f2bf(v1[0]); h1[1]=f2bf(v1[1]); h1[2]=f2bf(v1[2]); h1[3]=f2bf(v1[3]);
  *(us4*)(out + base) = h0;
  *(us4*)(out + base + 4) = h1;
  if(passes == 2){
    us4 l0, l1;
    l0[0]=f2bf(v0[0]-bf2f(h0[0])); l0[1]=f2bf(v0[1]-bf2f(h0[1]));
    l0[2]=f2bf(v0[2]-bf2f(h0[2])); l0[3]=f2bf(v0[3]-bf2f(h0[3]));
    l1[0]=f2bf(v1[0]-bf2f(h1[0])); l1[1]=f2bf(v1[1]-bf2f(h1[1]));
    l1[2]=f2bf(v1[2]-bf2f(h1[2])); l1[3]=f2bf(v1[3]-bf2f(h1[3]));
    *(us4*)(out + base + 512) = l0;
    *(us4*)(out + base + 516) = l1;
  }
}

// ---------------- bf16xbf16 GEMM-BT body (m97 structure) -------------------------
__device__ __forceinline__ void gemm_body(int m0, int n0,
    const u16* __restrict__ A, int lda,
    const u16* __restrict__ B, int ldb,
    const float* __restrict__ bias,
    float* __restrict__ C, int ldc, int mofs,
    int M, int N, int K){
  int tid = threadIdx.x;
  int lane = tid & 63, wave = tid >> 6;
  int wm = wave >> 1, wn = wave & 1;
  int lm = lane & 15, lq = lane >> 4;
  __shared__ __align__(16) u16 Asl[128*32];
  __shared__ __align__(16) u16 Bsl[128*32];
  f4v acc[4][4];
  #pragma unroll
  for(int i = 0; i < 4; i++)
    #pragma unroll
    for(int j = 0; j < 4; j++) acc[i][j] = (f4v){0.f,0.f,0.f,0.f};
  int e0 = (wave*2+0)*512 + lane*8;
  int e1 = (wave*2+1)*512 + lane*8;
  int r0 = e0 >> 5, c0 = e0 & 31;
  int r1 = e1 >> 5, c1 = e1 & 31;
  const u16* Ag0 = A + (size_t)imin(m0+r0, M-1)*lda + c0;
  const u16* Ag1 = A + (size_t)imin(m0+r1, M-1)*lda + c1;
  const u16* Bg0 = B + (size_t)imin(n0+r0, N-1)*ldb + c0;
  const u16* Bg1 = B + (size_t)imin(n0+r1, N-1)*ldb + c1;
  u16* Al0 = Asl + (wave*2+0)*512;
  u16* Al1 = Asl + (wave*2+1)*512;
  u16* Bl0 = Bsl + (wave*2+0)*512;
  u16* Bl1 = Bsl + (wave*2+1)*512;
  for(int k0 = 0; k0 < K; k0 += 32){
    __syncthreads();
    gll16(Ag0 + k0, Al0); gll16(Ag1 + k0, Al1);
    gll16(Bg0 + k0, Bl0); gll16(Bg1 + k0, Bl1);
    __syncthreads();
    s8v af[4], bfv[4];
    #pragma unroll
    for(int mi = 0; mi < 4; mi++)
      af[mi] = *(const s8v*)(Asl + (wm*64 + mi*16 + lm)*32 + lq*8);
    #pragma unroll
    for(int nj = 0; nj < 4; nj++)
      bfv[nj] = *(const s8v*)(Bsl + (wn*64 + nj*16 + lm)*32 + lq*8);
    #pragma unroll
    for(int mi = 0; mi < 4; mi++)
      #pragma unroll
      for(int nj = 0; nj < 4; nj++)
        acc[mi][nj] = __builtin_amdgcn_mfma_f32_16x16x32_bf16(af[mi], bfv[nj], acc[mi][nj], 0, 0, 0);
  }
  #pragma unroll
  for(int nj = 0; nj < 4; nj++){
    int n = n0 + wn*64 + nj*16 + lm;
    if(n < N){
      float bv = bias[n];
      #pragma unroll
      for(int mi = 0; mi < 4; mi++){
        #pragma unroll
        for(int rg = 0; rg < 4; rg++){
          int m = m0 + wm*64 + mi*16 + lq*4 + rg;
          if(m < M) C[(size_t)(m + mofs)*ldc + n] = acc[mi][nj][rg] + bv;
        }
      }
    }
  }
}

__global__ __launch_bounds__(256) void k_gemm_bf(
    const u16* __restrict__ A, int lda, const u16* __restrict__ B, int ldb,
    const float* __restrict__ bias, float* __restrict__ C, int ldc, int mofs,
    int M, int N, int K){
  gemm_body(blockIdx.x*128, blockIdx.y*128, A, lda, B, ldb, bias, C, ldc, mofs, M, N, K);
}

// logits GEMM: 1D grid, XCD-bijective swizzle
__global__ __launch_bounds__(256) void k_gemm_lg(
    const u16* __restrict__ A, int lda, const u16* __restrict__ B, int ldb,
    const float* __restrict__ bias, float* __restrict__ C, int ldc, int mofs,
    int M, int N, int K){
  int id = blockIdx.x;
  int x = id & 7, j = id >> 3;
  int m = j & 7, p = (j & ~7) | x;
  if(p * 128 >= N) return;
  gemm_body(m*128, p*128, A, lda, B, ldb, bias, C, ldc, mofs, M, N, K);
}

// ---------------- PERSISTENT encoder: 64 blocks x 1 wave, weights LDS-resident ---
// h-state fully step-versioned in hbfv (hi/lo bf16); hold = hi+lo reconstruction
__global__ __launch_bounds__(64) void k_encp(
    const float* __restrict__ gi_f, const float* __restrict__ gi_b,
    const u16* __restrict__ Wenc,
    const float* __restrict__ bhh_f, const float* __restrict__ bhh_b,
    u16* __restrict__ hbfv, u16* __restrict__ enc,
    unsigned* __restrict__ bars){
  int dir = blockIdx.x >> 5;
  int ub  = blockIdx.x & 31;
  int l = threadIdx.x;
  const float* giB = dir ? gi_b : gi_f;
  const float* bhh = dir ? bhh_b : bhh_f;
  const u16* Wslab = Wenc + ((size_t)(dir*32 + ub))*49152;
  __shared__ __align__(16) u16 WL[49152];   // 96 KB: weight slab, resident
  __shared__ __align__(16) u16 Ab[16384];   // 32 KB: one A chunk (hi+lo)
  #pragma unroll 1
  for(int i = 0; i < 96; i++) gll16(Wslab + i*512 + l*8, WL + i*512);
  int lm = l & 15, lq = l >> 4;
  for(int t = 0; t < SS; t++){
    int te = dir ? (SS-1-t) : t;
    const float* gi = giB + (size_t)(te*BB)*1536;
    const u16* Asrc = hbfv + (size_t)(t*2 + dir)*32768;       // versioned
    u16* Adst       = hbfv + (size_t)((t+1)*2 + dir)*32768;
    f4v acc[2][3];
    #pragma unroll
    for(int i = 0; i < 2; i++)
      #pragma unroll
      for(int j = 0; j < 3; j++) acc[i][j] = (f4v){0.f,0.f,0.f,0.f};
    for(int c = 0; c < 2; c++){
      __syncthreads();
      #pragma unroll 1
      for(int i = 0; i < 32; i++) gll16(Asrc + c*16384 + i*512 + l*8, Ab + i*512);
      __syncthreads();
      #pragma unroll
      for(int kf = 0; kf < 8; kf++){
        s8v a[2][2], bw[3][2];
        #pragma unroll
        for(int mf = 0; mf < 2; mf++)
          #pragma unroll
          for(int p = 0; p < 2; p++)
            a[mf][p] = *(const s8v*)(Ab + ((kf*2+mf)*2+p)*512 + l*8);
        #pragma unroll
        for(int g = 0; g < 3; g++)
          #pragma unroll
          for(int p = 0; p < 2; p++)
            bw[g][p] = *(const s8v*)(WL + c*24576 + ((kf*3+g)*2+p)*512 + l*8);
        #pragma unroll
        for(int mf = 0; mf < 2; mf++)
          #pragma unroll
          for(int g = 0; g < 3; g++){
            acc[mf][g] = __builtin_amdgcn_mfma_f32_16x16x32_bf16(a[mf][0], bw[g][0], acc[mf][g], 0, 0, 0);
            acc[mf][g] = __builtin_amdgcn_mfma_f32_16x16x32_bf16(a[mf][1], bw[g][0], acc[mf][g], 0, 0, 0);
            acc[mf][g] = __builtin_amdgcn_mfma_f32_16x16x32_bf16(a[mf][0], bw[g][1], acc[mf][g], 0, 0, 0);
          }
      }
    }
    __syncthreads();
    float* ghs = (float*)Ab;              // 6 KB, A chunk dead
    #pragma unroll
    for(int mf = 0; mf < 2; mf++)
      #pragma unroll
      for(int g = 0; g < 3; g++)
        #pragma unroll
        for(int rg = 0; rg < 4; rg++)
          ghs[(g*16 + lm)*32 + mf*16 + lq*4 + rg] = acc[mf][g][rg];
    __syncthreads();
    #pragma unroll
    for(int it = 0; it < 8; it++){
      int idx = it*64 + l;
      int b = idx & 31, ulu = idx >> 5;
      int u = ub*16 + ulu;
      float ghr = ghs[(ulu)*32 + b]      + bhh[u];
      float ghz = ghs[(16 + ulu)*32 + b] + bhh[512 + u];
      float ghn = ghs[(32 + ulu)*32 + b] + bhh[1024 + u];
      const float* gb = gi + b*1536 + u;
      float r = sigm(gb[0] + ghr);
      float z = sigm(gb[512] + ghz);
      float n = ftanh(gb[1024] + r*ghn);
      int kf = u >> 5, mf = b >> 4, l2 = ((u >> 3) & 3)*16 + (b & 15), e = u & 7;
      int base = (kf*2 + mf)*1024 + l2*8 + e;
      float hold = bf2f(Asrc[base]) + bf2f(Asrc[base + 512]);
      float h2 = (1.f - z)*n + z*hold;
      enc[(size_t)(b*SS + te)*1024 + dir*512 + u] = f2bf(h2);
      u16 hi = f2bf(h2);
      float lo = h2 - bf2f(hi);
      Adst[base]       = hi;
      Adst[base + 512] = f2bf(lo);
    }
    if(t < SS-1) gbarv(bars + dir*64 + t, 32u);
  }
}

// ---------------- state = tanh([hf,hb] @ Wfc^T + bfc); packs stV[0], AstV[0] -----
__global__ __launch_bounds__(256) void k_encfc(
    const u16* __restrict__ hbfv, const float* __restrict__ Wfc,
    const float* __restrict__ bfc, float* __restrict__ st0, u16* __restrict__ Ast0){
  int b = blockIdx.x;
  const u16* h0 = hbfv + (size_t)(SS*2 + 0)*32768;
  const u16* h1 = hbfv + (size_t)(SS*2 + 1)*32768;
  __shared__ __align__(16) float hc[1024];
  for(int i = threadIdx.x; i < 512; i += 256){
    int base = ((i>>5)*2 + (b>>4))*1024 + (((i>>3)&3)*16 + (b&15))*8 + (i&7);
    hc[i]       = bf2f(h0[base]) + bf2f(h0[base + 512]);
    hc[512 + i] = bf2f(h1[base]) + bf2f(h1[base + 512]);
  }
  __syncthreads();
  for(int u = threadIdx.x; u < 512; u += 256){
    const float* w = Wfc + u*1024;
    float a = 0.f;
    for(int k = 0; k < 1024; k += 4){
      f4v x = *(const f4v*)(hc + k);
      f4v wv = *(const f4v*)(w + k);
      a += x[0]*wv[0] + x[1]*wv[1] + x[2]*wv[2] + x[3]*wv[3];
    }
    float sv = ftanh(a + bfc[u]);
    st0[b*UU + u] = sv;
    u16 hi = f2bf(sv);
    float lo = sv - bf2f(hi);
    int kf = u >> 5, mf = b >> 4, l2 = ((u >> 3) & 3)*16 + (b & 15), e = u & 7;
    int base = (kf*2 + mf)*1024 + l2*8 + e;
    Ast0[base]       = hi;
    Ast0[base + 512] = f2bf(lo);
  }
}

// ---------------- PERSISTENT decoder: 32 blocks x 256 thr, versioned buffers -----
__global__ __launch_bounds__(256) void k_decp(
    float* __restrict__ stV, const float* __restrict__ P,
    const u16* __restrict__ enc, const u16* __restrict__ Wqp,
    const u16* __restrict__ Wdc, const u16* __restrict__ Wds,
    u16* __restrict__ ActxV, u16* __restrict__ AstV,
    float* __restrict__ qGpV,
    const float* __restrict__ giE, const float* __restrict__ bhh,
    u16* __restrict__ Xl, unsigned* __restrict__ bars){
  int bid = blockIdx.x;
  int tid = threadIdx.x;
  int l = tid & 63, w = tid >> 6;
  int lm = l & 15, lq = l >> 4;
  __shared__ __align__(16) u16 Ab[16384];    // 32 KB
  __shared__ __align__(16) u16 Bb[24576];    // 48 KB
  __shared__ float qvt[512];
  __shared__ float wv[64];
  int ubq = bid >> 1, cq = bid & 1;
  const u16* Wq   = Wqp + (size_t)ubq*32768 + cq*16384;
  const u16* Wdcs = Wdc + (size_t)bid*49152;
  const u16* Wdss = Wds + (size_t)bid*49152;
  for(int t = 0; t < TT-1; t++){
    const u16* AstI = AstV + (size_t)t*32768;           // versioned
    u16* AstO       = AstV + (size_t)(t+1)*32768;
    const float* stin = stV + (size_t)t*16384;
    float* stout      = stV + (size_t)(t+1)*16384;
    u16* Actx_t   = ActxV + (size_t)t*32768;
    float* qGp_t  = qGpV + (size_t)t*32768;
    // ======== q phase: block=(ubq,cq); 4-wave staging, wave0 MFMA ==============
    #pragma unroll 1
    for(int i = 0; i < 16; i++){
      int r = w*16 + i;
      if(r < 32) gll16(AstI + cq*16384 + r*512 + l*8, Ab + r*512);
      else       gll16(Wq + (size_t)(r-32)*512 + l*8, Bb + (r-32)*512);
    }
    __syncthreads();
    if(w == 0){
      f4v qa[2][2];
      #pragma unroll
      for(int i = 0; i < 2; i++)
        #pragma unroll
        for(int j = 0; j < 2; j++) qa[i][j] = (f4v){0.f,0.f,0.f,0.f};
      #pragma unroll
      for(int kf = 0; kf < 8; kf++){
        s8v a[2][2], bw[2][2];
        #pragma unroll
        for(int mf = 0; mf < 2; mf++)
          #pragma unroll
          for(int p = 0; p < 2; p++){
            a[mf][p]  = *(const s8v*)(Ab + ((kf*2+mf)*2+p)*512 + l*8);
            bw[mf][p] = *(const s8v*)(Bb + ((kf*2+mf)*2+p)*512 + l*8);
          }
        #pragma unroll
        for(int mf = 0; mf < 2; mf++)
          #pragma unroll
          for(int g = 0; g < 2; g++){
            qa[mf][g] = __builtin_amdgcn_mfma_f32_16x16x32_bf16(a[mf][0], bw[g][0], qa[mf][g], 0, 0, 0);
            qa[mf][g] = __builtin_amdgcn_mfma_f32_16x16x32_bf16(a[mf][1], bw[g][0], qa[mf][g], 0, 0, 0);
            qa[mf][g] = __builtin_amdgcn_mfma_f32_16x16x32_bf16(a[mf][0], bw[g][1], qa[mf][g], 0, 0, 0);
          }
      }
      float* qout = qGp_t + cq*16384;
      #pragma unroll
      for(int mf = 0; mf < 2; mf++)
        #pragma unroll
        for(int g = 0; g < 2; g++)
          #pragma unroll
          for(int rg = 0; rg < 4; rg++){
            int a_ = ubq*32 + g*16 + lm;
            int b_ = mf*16 + lq*4 + rg;
            qout[b_*512 + (a_ & 31)*16 + (a_ >> 5)] = qa[mf][g][rg];
          }
    }
    gbarv(bars + 128 + t*3 + 0, 32u);
    // ======== attn phase: b = bid ==============================================
    {
      int b = bid;
      for(int i = tid; i < 512; i += 256)
        qvt[i] = qGp_t[b*512 + i] + qGp_t[16384 + b*512 + i];
      __syncthreads();
      {
        int s = tid >> 2, part = tid & 3;
        const float* Pb = P + (size_t)(b*SS + s)*512 + part*128;
        float ps = 0.f;
        #pragma unroll 8
        for(int i = 0; i < 128; i += 4){
          f4v pv = *(const f4v*)(Pb + i);
          int a0 = part*128 + i;
          ps += ftanh(pv[0] + qvt[((a0+0)&31)*16 + ((a0+0)>>5)]);
          ps += ftanh(pv[1] + qvt[((a0+1)&31)*16 + ((a0+1)>>5)]);
          ps += ftanh(pv[2] + qvt[((a0+2)&31)*16 + ((a0+2)>>5)]);
          ps += ftanh(pv[3] + qvt[((a0+3)&31)*16 + ((a0+3)>>5)]);
        }
        ps += __shfl_xor(ps, 1);
        ps += __shfl_xor(ps, 2);
        if(part == 0) wv[s] = ps;
      }
      __syncthreads();
      if(tid < 64){
        float sc = wv[tid];
        float m = sc;
        for(int o = 32; o > 0; o >>= 1) m = fmaxf(m, __shfl_xor(m, o));
        float e = __expf(sc - m);
        float ssum = e;
        for(int o = 32; o > 0; o >>= 1) ssum += __shfl_xor(ssum, o);
        wv[tid] = e / ssum;
      }
      __syncthreads();
      int rowX = t*BB + b;
      const u16* eb = enc + (size_t)(b*SS)*1024 + tid;
      float a0=0.f, a1=0.f, a2=0.f, a3=0.f;
      #pragma unroll 4
      for(int s2 = 0; s2 < SS; s2++){
        float wgt = wv[s2];
        const u16* r = eb + (size_t)s2*1024;
        a0 += wgt*bf2f(r[0]);
        a1 += wgt*bf2f(r[256]);
        a2 += wgt*bf2f(r[512]);
        a3 += wgt*bf2f(r[768]);
      }
      float av[4] = {a0, a1, a2, a3};
      #pragma unroll
      for(int jj = 0; jj < 4; jj++){
        int j = jj*256 + tid;
        u16 cb = f2bf(av[jj]);
        Xl[(size_t)rowX*1856 + 512 + j] = cb;
        int kf = j >> 5, mf = b >> 4, l2 = ((j >> 3) & 3)*16 + (b & 15), e = j & 7;
        Actx_t[(size_t)(kf*2 + mf)*512 + l2*8 + e] = cb;
      }
    }
    gbarv(bars + 128 + t*3 + 1, 32u);
    // ======== gru phase: ub = bid; kf split across 4 waves =====================
    {
      int ub = bid;
      f4v accI[2][3], accH[2][3];
      #pragma unroll
      for(int i = 0; i < 2; i++)
        #pragma unroll
        for(int j = 0; j < 3; j++){
          accI[i][j] = (f4v){0.f,0.f,0.f,0.f};
          accH[i][j] = (f4v){0.f,0.f,0.f,0.f};
        }
      #pragma unroll 1
      for(int sp = 0; sp < 4; sp++){
        const u16* Asub = (sp < 2) ? (Actx_t + sp*16384) : (AstI + (sp-2)*16384);
        const u16* Bsub = (sp < 2) ? (Wdcs + sp*24576) : (Wdss + (sp-2)*24576);
        __syncthreads();
        #pragma unroll 1
        for(int i = 0; i < 20; i++){
          int r = w*20 + i;
          const u16* src = (r < 32) ? (Asub + r*512) : (Bsub + (size_t)(r-32)*512);
          u16* dst = (r < 32) ? (Ab + r*512) : (Bb + (r-32)*512);
          gll16(src + l*8, dst);
        }
        __syncthreads();
        if(sp < 2){
          #pragma unroll
          for(int kk = 0; kk < 4; kk++){
            int kf = w*4 + kk;
            s8v a0 = *(const s8v*)(Ab + (kf*2+0)*512 + l*8);
            s8v a1 = *(const s8v*)(Ab + (kf*2+1)*512 + l*8);
            s8v b0 = *(const s8v*)(Bb + (kf*3+0)*512 + l*8);
            s8v b1 = *(const s8v*)(Bb + (kf*3+1)*512 + l*8);
            s8v b2 = *(const s8v*)(Bb + (kf*3+2)*512 + l*8);
            accI[0][0] = __builtin_amdgcn_mfma_f32_16x16x32_bf16(a0, b0, accI[0][0], 0, 0, 0);
            accI[0][1] = __builtin_amdgcn_mfma_f32_16x16x32_bf16(a0, b1, accI[0][1], 0, 0, 0);
            accI[0][2] = __builtin_amdgcn_mfma_f32_16x16x32_bf16(a0, b2, accI[0][2], 0, 0, 0);
            accI[1][0] = __builtin_amdgcn_mfma_f32_16x16x32_bf16(a1, b0, accI[1][0], 0, 0, 0);
            accI[1][1] = __builtin_amdgcn_mfma_f32_16x16x32_bf16(a1, b1, accI[1][1], 0, 0, 0);
            accI[1][2] = __builtin_amdgcn_mfma_f32_16x16x32_bf16(a1, b2, accI[1][2], 0, 0, 0);
          }
        } else {
          #pragma unroll
          for(int kk = 0; kk < 2; kk++){
            int kf = w*2 + kk;
            s8v a[2][2], bw[3][2];
            #pragma unroll
            for(int mf = 0; mf < 2; mf++)
              #pragma unroll
              for(int p = 0; p < 2; p++)
                a[mf][p] = *(const s8v*)(Ab + ((kf*2+mf)*2+p)*512 + l*8);
            #pragma unroll
            for(int g = 0; g < 3; g++)
              #pragma unroll
              for(int p = 0; p < 2; p++)
                bw[g][p] = *(const s8v*)(Bb + ((kf*3+g)*2+p)*512 + l*8);
            #pragma unroll
            for(int mf = 0; mf < 2; mf++)
              #pragma unroll
              for(int g = 0; g < 3; g++){
                accH[mf][g] = __builtin_amdgcn_mfma_f32_16x16x32_bf16(a[mf][0], bw[g][0], accH[mf][g], 0, 0, 0);
                accH[mf][g] = __builtin_amdgcn_mfma_f32_16x16x32_bf16(a[mf][1], bw[g][0], accH[mf][g], 0, 0, 0);
                accH[mf][g] = __builtin_amdgcn_mfma_f32_16x16x32_bf16(a[mf][0], bw[g][1], accH[mf][g], 0, 0, 0);
              }
          }
        }
      }
      __syncthreads();
      float* ghsI = (float*)Bb;                 // 4 x 6 KB partials
      float* ghsH = (float*)Ab;                 // 4 x 6 KB partials
      #pragma unroll
      for(int mf = 0; mf < 2; mf++)
        #pragma unroll
        for(int g = 0; g < 3; g++)
          #pragma unroll
          for(int rg = 0; rg < 4; rg++){
            int o = w*1536 + (g*16 + lm)*32 + mf*16 + lq*4 + rg;
            ghsI[o] = accI[mf][g][rg];
            ghsH[o] = accH[mf][g][rg];
          }
      __syncthreads();
      #pragma unroll
      for(int it = 0; it < 2; it++){
        int idx = it*256 + tid;
        int b2 = idx & 31, ulu = idx >> 5;
        int u = ub*16 + ulu;
        int xrow = t*BB + b2;
        float gIr=0.f, gIz=0.f, gIn=0.f, gHr=0.f, gHz=0.f, gHn=0.f;
        #pragma unroll
        for(int ww = 0; ww < 4; ww++){
          int o = ww*1536;
          gIr += ghsI[o + (ulu)*32 + b2];
          gIz += ghsI[o + (16 + ulu)*32 + b2];
          gIn += ghsI[o + (32 + ulu)*32 + b2];
          gHr += ghsH[o + (ulu)*32 + b2];
          gHz += ghsH[o + (16 + ulu)*32 + b2];
          gHn += ghsH[o + (32 + ulu)*32 + b2];
        }
        const float* ge = giE + (size_t)xrow*1536 + u;
        gIr += ge[0]; gIz += ge[512]; gIn += ge[1024];
        gHr += bhh[u]; gHz += bhh[512 + u]; gHn += bhh[1024 + u];
        float r = sigm(gIr + gHr);
        float z = sigm(gIz + gHz);
        float n = ftanh(gIn + r*gHn);
        float hold = stin[b2*512 + u];
        float h2 = (1.f - z)*n + z*hold;
        stout[b2*512 + u] = h2;
        Xl[(size_t)xrow*1856 + u] = f2bf(h2);
        u16 hi = f2bf(h2);
        float lo = h2 - bf2f(hi);
        int kf2 = u >> 5, mf2 = b2 >> 4, l2 = ((u >> 3) & 3)*16 + (b2 & 15), e = u & 7;
        int base = (kf2*2 + mf2)*1024 + l2*8 + e;
        AstO[base]       = hi;
        AstO[base + 512] = f2bf(lo);
      }
    }
    if(t < TT-2) gbarv(bars + 128 + t*3 + 2, 32u);
  }
}

extern "C" void kernel_launch(void* const* d_in, const int* in_sizes, int n_in,
                              void* d_out, int out_size, void* d_ws, size_t ws_size,
                              hipStream_t stream){
  (void)in_sizes; (void)n_in; (void)out_size; (void)ws_size;
  const float* emb_src = (const float*)d_in[0];
  const float* emb_trg = (const float*)d_in[1];
  const float* eWih_f  = (const float*)d_in[2];
  const float* eWhh_f  = (const float*)d_in[3];
  const float* ebih_f  = (const float*)d_in[4];
  const float* ebhh_f  = (const float*)d_in[5];
  const float* eWih_b  = (const float*)d_in[6];
  const float* eWhh_b  = (const float*)d_in[7];
  const float* ebih_b  = (const float*)d_in[8];
  const float* ebhh_b  = (const float*)d_in[9];
  const float* Wfc     = (const float*)d_in[10];
  const float* bfc     = (const float*)d_in[11];
  const float* attn_W  = (const float*)d_in[12];
  const float* attn_b  = (const float*)d_in[13];
  const float* dWih    = (const float*)d_in[14];
  const float* dWhh    = (const float*)d_in[15];
  const float* dbih    = (const float*)d_in[16];
  const float* dbhh    = (const float*)d_in[17];
  const float* dWfc    = (const float*)d_in[18];
  const float* dbfc    = (const float*)d_in[19];
  const int* source    = (const int*)d_in[20];
  const int* target    = (const int*)d_in[21];
  float* out = (float*)d_out;
  float* wsf = (float*)d_ws;

  // ---- persistent f32 ----
  float* P    = wsf;                                   // 2048x512
  float* giE  = P + (size_t)2048*512;                  // 992x1536
  // ---- persistent u16 ----
  u16* enc   = (u16*)(giE + (size_t)992*1536);         // (B,S,2U)
  u16* Xl    = enc + (size_t)2048*1024;                // 992x1856
  u16* Xsrc  = Xl + (size_t)992*1856;                  // 2048x320
  u16* WihF  = Xsrc + (size_t)2048*320;                // 1536x320
  u16* WihB  = WihF + (size_t)1536*320;
  u16* WihE  = WihB + (size_t)1536*320;
  u16* AttnW = WihE + (size_t)1536*320;                // 512x1024
  u16* Wenc  = AttnW + (size_t)512*1024;               // 2dir x 32ub x 49152
  u16* Wdc   = Wenc + (size_t)2*32*49152;              // 32ub x 49152
  u16* Wds   = Wdc + (size_t)32*49152;                 // 32ub x 49152
  u16* Wqp   = Wds + (size_t)32*49152;                 // 16ub x 32768
  unsigned* bars = (unsigned*)(Wqp + (size_t)16*32768);// 256 u32
  u16* tb    = (u16*)(bars + 256);                     // tail overlap region
  // -- tail, encoder phase: gi + versioned h-state
  float* gi_f = (float*)tb;                            // 2048x1536
  float* gi_b = gi_f + (size_t)2048*1536;
  u16* hbfv  = (u16*)(gi_b + (size_t)2048*1536);       // 65 x 2 x 32768 (versioned)
  // -- tail, decoder phase (gi dead): versioned decoder buffers
  float* stV  = (float*)tb;                            // 32 x 16384
  float* qGpV = stV + (size_t)32*16384;                // 31 x 32768
  u16* ActxV  = (u16*)(qGpV + (size_t)31*32768);       // 31 x 32768
  u16* AstV   = ActxV + (size_t)31*32768;              // 32 x 32768
  // -- tail, final: bf16 dWfc
  u16* WfcB  = tb;                                     // 30000x1856
  u16* EmbT  = Xsrc;                                   // reuse after gi GEMMs

  k_init<<<3750, 256, 0, stream>>>(out, Xl, (float*)hbfv, bars);
  k_embsrc<<<2560, 256, 0, stream>>>(emb_src, source, Xsrc);
  k_cvt<<<1536, 256, 0, stream>>>(eWih_f, 300, 0, 300, WihF, 320);
  k_cvt<<<1536, 256, 0, stream>>>(eWih_b, 300, 0, 300, WihB, 320);
  k_cvt<<<1536, 256, 0, stream>>>(dWih, 1324, 0, 300, WihE, 320);
  k_cvt<<<512, 256, 0, stream>>>(attn_W, 1536, 512, 1024, AttnW, 1024);
  // fragment-linear recurrent weights
  k_wprep<<<384, 256, 0, stream>>>(eWhh_f, 512, 0, 512, 3, 16, 16, 2, 98304, Wenc);
  k_wprep<<<384, 256, 0, stream>>>(eWhh_b, 512, 0, 512, 3, 16, 16, 2, 98304, Wenc + (size_t)32*49152);
  k_wprep<<<768, 256, 0, stream>>>(dWih, 1324, 300, 512, 3, 16, 32, 1, 196608, Wdc);
  k_wprep<<<384, 256, 0, stream>>>(dWhh, 512, 0, 512, 3, 16, 16, 2, 98304, Wds);
  k_wprep<<<128, 256, 0, stream>>>(attn_W, 1536, 0, 16, 2, 32, 16, 2, 32768, Wqp);
  // gi = Xsrc @ Wih^T + bih (both dirs)
  k_gemm_bf<<<dim3(16,12), 256, 0, stream>>>(Xsrc, 320, WihF, 320, ebih_f, gi_f, 1536, 0, 2048, 1536, 320);
  k_gemm_bf<<<dim3(16,12), 256, 0, stream>>>(Xsrc, 320, WihB, 320, ebih_b, gi_b, 1536, 0, 2048, 1536, 320);
  // persistent encoder: all 64 steps in one launch
  k_encp<<<64, 64, 0, stream>>>(gi_f, gi_b, Wenc, ebhh_f, ebhh_b, hbfv, enc, bars);
  k_encfc<<<BB, 256, 0, stream>>>(hbfv, Wfc, bfc, stV, AstV);
  k_gemm_bf<<<dim3(16,4), 256, 0, stream>>>(enc, 1024, AttnW, 1024, attn_b, P, 512, 0, 2048, 512, 1024);
  k_embT<<<1240, 256, 0, stream>>>(emb_trg, target, EmbT, Xl);
  k_gemm_bf<<<dim3(8,12), 256, 0, stream>>>(EmbT, 320, WihE, 320, dbih, giE, 1536, 0, 992, 1536, 320);
  // persistent decoder: all 31 steps in one launch
  k_decp<<<32, 256, 0, stream>>>(stV, P, enc, Wqp, Wdc, Wds, ActxV, AstV, qGpV,
                                 giE, dbhh, Xl, bars);
  // WfcB cvt deferred here: overlaps (dead) gi/hbfv/decoder buffers
  k_cvt<<<30000, 256, 0, stream>>>(dWfc, 1836, 0, 1836, WfcB, 1856);
  k_gemm_lg<<<1920, 256, 0, stream>>>(Xl, 1856, WfcB, 1856, dbfc, out, VTT, 32, 992, VTT, 1856);
}